// Round 14
// baseline (269.506 us; speedup 1.0000x reference)
//
#include <hip/hip_runtime.h>
#include <hip/hip_cooperative_groups.h>

namespace cg = cooperative_groups;

// LoRA forward: out = (h @ B^T) @ A^T, h: (16384, 4096) f32, rank 16.
// R14: cooperative fusion of the proven R10 pair. Phase 1 = R10-K1 verbatim
// (bf16 MFMA, wave-private LDS ring, counted vmcnt(6), no k-loop barriers),
// hr -> d_ws + threadfence. grid.sync() replaces the kernel boundary.
// Phase 2 = R10-K2 verbatim structure (A-frag, NT stores), 2 tiles/block,
// hr via NT loads (R12-proven cross-XCD consumer pattern).

constexpr int  D  = 4096;
constexpr int  RK = 16;
constexpr long M  = 16384;

typedef float f32x4 __attribute__((ext_vector_type(4)));
typedef short bf16x8 __attribute__((ext_vector_type(8)));
typedef int   i32x4 __attribute__((ext_vector_type(4)));

__device__ __forceinline__ void gload_lds16(const float* src, float* ldsdst) {
  __builtin_amdgcn_global_load_lds(
      (const __attribute__((address_space(1))) void*)src,
      (__attribute__((address_space(3))) void*)ldsdst, 16, 0, 0);
}

__device__ __forceinline__ float dot4(float4 a, float4 b) {
  return a.x * b.x + a.y * b.y + a.z * b.z + a.w * b.w;
}
__device__ __forceinline__ float dot4e(f32x4 a, float4 b) {
  return a.x * b.x + a.y * b.y + a.z * b.z + a.w * b.w;
}

__device__ __forceinline__ unsigned cvt_pk_bf16(float lo, float hi) {
  unsigned r;
  asm("v_cvt_pk_bf16_f32 %0, %1, %2" : "=v"(r) : "v"(lo), "v"(hi));
  return r;
}

__device__ __forceinline__ bf16x8 to_bf16x8(float4 a, float4 b) {
  i32x4 u;
  u.x = (int)cvt_pk_bf16(a.x, a.y);
  u.y = (int)cvt_pk_bf16(a.z, a.w);
  u.z = (int)cvt_pk_bf16(b.x, b.y);
  u.w = (int)cvt_pk_bf16(b.z, b.w);
  return __builtin_bit_cast(bf16x8, u);
}

constexpr int KC   = 32;            // k per chunk (one MFMA)
constexpr int NCH1 = 2048 / KC;     // 64 chunks per wave (k-half)

__global__ __launch_bounds__(256, 4) void lora_coop(
    const float* __restrict__ h,
    const float* __restrict__ matA,   // (D, RK) row-major
    const float* __restrict__ matB,   // (RK, D) row-major
    float* __restrict__ out,
    float* __restrict__ hr) {         // (M, RK) in d_ws
  __shared__ float sH[4][4][16][KC];  // [wave][ringbuf][row][k] 32 KB
  __shared__ float part[4][16][RK];   // [wave][row][rank]        4 KB

  const int tid = threadIdx.x;
  const int wu  = __builtin_amdgcn_readfirstlane(tid >> 6);  // wave 0..3
  const int l   = tid & 63;

  // ================= Phase 1: hr = h @ B^T (R10-K1 verbatim) ===============
  {
    const int t  = wu & 1;            // row-tile
    const int q  = wu >> 1;           // k-half
    const long rbase = (long)blockIdx.x * 32;
    const long rowt  = rbase + t * 16;
    const int  k0    = q * 2048;

    auto STAGE = [&](int b, int c) {
#pragma unroll
      for (int ld = 0; ld < 2; ++ld) {
        const int R  = ld * 8 + (l >> 3);
        const int sd = l & 7;
        const float* src =
            h + (rowt + R) * (long)D + k0 + c * KC + ((sd ^ (R & 7)) * 4);
        gload_lds16(src, &sH[wu][b][ld * 8][0]);
      }
    };
    auto BLOAD = [&](int c, float4& b0, float4& b1) {
      const float* bp = matB + (long)(l & 15) * D + k0 + c * KC + (l >> 4) * 8;
      b0 = *reinterpret_cast<const float4*>(bp);
      b1 = *reinterpret_cast<const float4*>(bp + 4);
    };

    f32x4 acc = {0.f, 0.f, 0.f, 0.f};
    float4 bc0, bc1, bn0, bn1;

    STAGE(0, 0);
    BLOAD(0, bc0, bc1);
    STAGE(1, 1);

#pragma unroll 1
    for (int c = 0; c < NCH1; ++c) {
      const int cb = (c + 1 < NCH1) ? c + 1 : NCH1 - 1;   // clamped prefetch
      const int cs = (c + 2 < NCH1) ? c + 2 : NCH1 - 1;
      BLOAD(cb, bn0, bn1);            // B(c+1): 2 loads
      STAGE((c + 2) & 3, cs);         // h(c+2): 2 loads
      // queue: h(c),B(c),h(c+1),B(c+1),h(c+2) = 10 outstanding
      asm volatile("s_waitcnt vmcnt(6)" ::: "memory");
      __builtin_amdgcn_sched_barrier(0);

      const float* abase = &sH[wu][c & 3][l & 15][0];
      const int sj = (l >> 4) * 2, r7 = l & 7;
      const float4 a0 =
          *reinterpret_cast<const float4*>(abase + ((sj ^ r7) * 4));
      const float4 a1 =
          *reinterpret_cast<const float4*>(abase + (((sj + 1) ^ r7) * 4));

      const bf16x8 af = to_bf16x8(a0, a1);
      const bf16x8 bf = to_bf16x8(bc0, bc1);
      acc = __builtin_amdgcn_mfma_f32_16x16x32_bf16(af, bf, acc, 0, 0, 0);

      bc0 = bn0;
      bc1 = bn1;
    }

    asm volatile("s_waitcnt vmcnt(0)" ::: "memory");
    // C/D layout: col(rank) = l&15, row = (l>>4)*4 + j
#pragma unroll
    for (int j = 0; j < 4; ++j) part[wu][(l >> 4) * 4 + j][l & 15] = acc[j];
    __syncthreads();

    // tile0 = waves {0,2}, tile1 = waves {1,3}; write hr coalesced
#pragma unroll
    for (int e = tid; e < 512; e += 256) {
      const int row = e >> 4, rk = e & 15, tl = row >> 4;
      const float s = part[tl][row & 15][rk] + part[tl + 2][row & 15][rk];
      hr[(rbase + row) * RK + rk] = s;
    }
  }

  // ================= boundary: device-scope release + grid barrier =========
  __threadfence();
  cg::this_grid().sync();

  // ================= Phase 2: out = hr @ A^T (R10-K2 verbatim) =============
#pragma unroll 1
  for (int s = 0; s < 2; ++s) {
    const int k2tile = (int)blockIdx.x + s * 512;   // 1024 tiles total
    const int cs  = k2tile & 3;                     // column slice (1024 cols)
    const long row0 = (long)(k2tile >> 2) * 64;
    const int c0 = cs * 1024 + tid * 4;             // 4 contiguous cols

    float4 a[4][4];  // A rows for my 4 cols: reused 64x (L2-hot)
#pragma unroll
    for (int j = 0; j < 4; ++j)
#pragma unroll
      for (int qq = 0; qq < 4; ++qq)
        a[j][qq] = *reinterpret_cast<const float4*>(
            matA + (long)(c0 + j) * RK + qq * 4);

#pragma unroll 4
    for (int rr = 0; rr < 64; ++rr) {
      const f32x4* hv =
          reinterpret_cast<const f32x4*>(hr + (row0 + rr) * RK);
      // NT loads: bypass per-XCD L2 (cross-block producer; R12-proven)
      const f32x4 h0 = __builtin_nontemporal_load(hv);
      const f32x4 h1 = __builtin_nontemporal_load(hv + 1);
      const f32x4 h2 = __builtin_nontemporal_load(hv + 2);
      const f32x4 h3 = __builtin_nontemporal_load(hv + 3);
      f32x4 o;
      o.x = dot4e(h0, a[0][0]) + dot4e(h1, a[0][1]) + dot4e(h2, a[0][2]) +
            dot4e(h3, a[0][3]);
      o.y = dot4e(h0, a[1][0]) + dot4e(h1, a[1][1]) + dot4e(h2, a[1][2]) +
            dot4e(h3, a[1][3]);
      o.z = dot4e(h0, a[2][0]) + dot4e(h1, a[2][1]) + dot4e(h2, a[2][2]) +
            dot4e(h3, a[2][3]);
      o.w = dot4e(h0, a[3][0]) + dot4e(h1, a[3][1]) + dot4e(h2, a[3][2]) +
            dot4e(h3, a[3][3]);
      __builtin_nontemporal_store(
          o, reinterpret_cast<f32x4*>(out + (row0 + rr) * (long)D + c0));
    }
  }
}

extern "C" void kernel_launch(void* const* d_in, const int* in_sizes, int n_in,
                              void* d_out, int out_size, void* d_ws,
                              size_t ws_size, hipStream_t stream) {
  const float* h    = (const float*)d_in[0];
  const float* matA = (const float*)d_in[1];
  const float* matB = (const float*)d_in[2];
  float* out        = (float*)d_out;
  float* hr         = (float*)d_ws;   // M * RK * 4 = 1 MiB scratch

  void* args[] = {(void*)&h, (void*)&matA, (void*)&matB,
                  (void*)&out, (void*)&hr};
  hipLaunchCooperativeKernel((void*)lora_coop, dim3((int)(M / 32)),
                             dim3(256), args, 0, stream);
}

// Round 15
// 96.105 us; speedup vs baseline: 2.8043x; 2.8043x over previous
//
#include <hip/hip_runtime.h>

// LoRA forward: out = (h @ B^T) @ A^T, h: (16384, 4096) f32, rank 16.
// R15 = R10 with K1 occupancy doubled: block = 16 rows, wave = k-quarter
// (1024 blocks, 4 blocks/CU, 16 waves/CU). Same proven barrier-free MFMA
// pipeline (wave-private LDS ring, counted vmcnt(6)). K2 unchanged.

constexpr int  D  = 4096;
constexpr int  RK = 16;
constexpr long M  = 16384;

typedef float f32x4 __attribute__((ext_vector_type(4)));
typedef short bf16x8 __attribute__((ext_vector_type(8)));
typedef int   i32x4 __attribute__((ext_vector_type(4)));

__device__ __forceinline__ void gload_lds16(const float* src, float* ldsdst) {
  __builtin_amdgcn_global_load_lds(
      (const __attribute__((address_space(1))) void*)src,
      (__attribute__((address_space(3))) void*)ldsdst, 16, 0, 0);
}

__device__ __forceinline__ float dot4(float4 a, float4 b) {
  return a.x * b.x + a.y * b.y + a.z * b.z + a.w * b.w;
}

__device__ __forceinline__ unsigned cvt_pk_bf16(float lo, float hi) {
  unsigned r;
  asm("v_cvt_pk_bf16_f32 %0, %1, %2" : "=v"(r) : "v"(lo), "v"(hi));
  return r;
}

__device__ __forceinline__ bf16x8 to_bf16x8(float4 a, float4 b) {
  i32x4 u;
  u.x = (int)cvt_pk_bf16(a.x, a.y);
  u.y = (int)cvt_pk_bf16(a.z, a.w);
  u.z = (int)cvt_pk_bf16(b.x, b.y);
  u.w = (int)cvt_pk_bf16(b.z, b.w);
  return __builtin_bit_cast(bf16x8, u);
}

// ---------------------------------------------------------------- K1 -------
// Block = 16 rows; wave wu owns k-quarter [wu*1024, wu*1024+1024).
constexpr int KC   = 32;     // k per chunk (one MFMA)
constexpr int NCHQ = 32;     // chunks per k-quarter

__global__ __launch_bounds__(256, 4) void lora_k1(
    const float* __restrict__ h,
    const float* __restrict__ matB,   // (RK, D) row-major
    float* __restrict__ hr) {         // (M, RK)
  __shared__ float sH[4][4][16][KC];  // [wave][ringbuf][row][k] 32 KB
  __shared__ float part[4][16][RK];   // [wave][row][rank]        4 KB

  const int tid = threadIdx.x;
  const int wu  = __builtin_amdgcn_readfirstlane(tid >> 6);  // wave 0..3
  const int l   = tid & 63;
  const long rbase = (long)blockIdx.x * 16;
  const int  k0    = wu * 1024;       // wave's k-quarter

  auto STAGE = [&](int b, int c) {
#pragma unroll
    for (int ld = 0; ld < 2; ++ld) {
      const int R  = ld * 8 + (l >> 3);
      const int sd = l & 7;
      const float* src =
          h + (rbase + R) * (long)D + k0 + c * KC + ((sd ^ (R & 7)) * 4);
      gload_lds16(src, &sH[wu][b][ld * 8][0]);
    }
  };
  auto BLOAD = [&](int c, float4& b0, float4& b1) {
    const float* bp = matB + (long)(l & 15) * D + k0 + c * KC + (l >> 4) * 8;
    b0 = *reinterpret_cast<const float4*>(bp);
    b1 = *reinterpret_cast<const float4*>(bp + 4);
  };

  f32x4 acc = {0.f, 0.f, 0.f, 0.f};
  float4 bc0, bc1, bn0, bn1;

  STAGE(0, 0);
  BLOAD(0, bc0, bc1);
  STAGE(1, 1);

#pragma unroll 1
  for (int c = 0; c < NCHQ; ++c) {
    const int cb = (c + 1 < NCHQ) ? c + 1 : NCHQ - 1;   // clamped prefetch
    const int cs = (c + 2 < NCHQ) ? c + 2 : NCHQ - 1;
    BLOAD(cb, bn0, bn1);            // B(c+1): 2 loads
    STAGE((c + 2) & 3, cs);         // h(c+2): 2 loads
    // queue: h(c),B(c),h(c+1),B(c+1),h(c+2) = 10 outstanding
    asm volatile("s_waitcnt vmcnt(6)" ::: "memory");
    __builtin_amdgcn_sched_barrier(0);

    const float* abase = &sH[wu][c & 3][l & 15][0];
    const int sj = (l >> 4) * 2, r7 = l & 7;
    const float4 a0 =
        *reinterpret_cast<const float4*>(abase + ((sj ^ r7) * 4));
    const float4 a1 =
        *reinterpret_cast<const float4*>(abase + (((sj + 1) ^ r7) * 4));

    const bf16x8 af = to_bf16x8(a0, a1);
    const bf16x8 bf = to_bf16x8(bc0, bc1);
    acc = __builtin_amdgcn_mfma_f32_16x16x32_bf16(af, bf, acc, 0, 0, 0);

    bc0 = bn0;
    bc1 = bn1;
  }

  asm volatile("s_waitcnt vmcnt(0)" ::: "memory");
  // C/D layout: col(rank) = l&15, row = (l>>4)*4 + j
#pragma unroll
  for (int j = 0; j < 4; ++j) part[wu][(l >> 4) * 4 + j][l & 15] = acc[j];
  __syncthreads();

  // reduce 4 k-quarters; 256 thr = 16 rows x 16 ranks; coalesced 1-KB store
  {
    const int row = tid >> 4, rk = tid & 15;
    float s = 0.f;
#pragma unroll
    for (int w2 = 0; w2 < 4; ++w2) s += part[w2][row][rk];
    hr[(rbase + row) * RK + rk] = s;
  }
}

// ---------------------------------------------------------------- K2 -------
__global__ __launch_bounds__(256) void lora_k2(
    const float* __restrict__ hr,     // (M, RK)
    const float* __restrict__ matA,   // (D, RK) row-major
    float* __restrict__ out) {
  const int tid = threadIdx.x;
  const int cs  = blockIdx.x & 3;          // column slice (1024 cols)
  const long row0 = (long)(blockIdx.x >> 2) * 64;
  const int c0 = cs * 1024 + tid * 4;      // 4 contiguous cols per thread

  float4 a[4][4];  // A rows for my 4 cols: 64 VGPRs, reused 64x
#pragma unroll
  for (int j = 0; j < 4; ++j)
#pragma unroll
    for (int qq = 0; qq < 4; ++qq)
      a[j][qq] = *reinterpret_cast<const float4*>(
          matA + (long)(c0 + j) * RK + qq * 4);

#pragma unroll 4
  for (int rr = 0; rr < 64; ++rr) {
    const float4* hv =
        reinterpret_cast<const float4*>(hr + (row0 + rr) * RK);  // uniform
    const float4 h0 = hv[0], h1 = hv[1], h2 = hv[2], h3 = hv[3];
    f32x4 o;
    o.x = dot4(h0, a[0][0]) + dot4(h1, a[0][1]) + dot4(h2, a[0][2]) +
          dot4(h3, a[0][3]);
    o.y = dot4(h0, a[1][0]) + dot4(h1, a[1][1]) + dot4(h2, a[1][2]) +
          dot4(h3, a[1][3]);
    o.z = dot4(h0, a[2][0]) + dot4(h1, a[2][1]) + dot4(h2, a[2][2]) +
          dot4(h3, a[2][3]);
    o.w = dot4(h0, a[3][0]) + dot4(h1, a[3][1]) + dot4(h2, a[3][2]) +
          dot4(h3, a[3][3]);
    __builtin_nontemporal_store(
        o, reinterpret_cast<f32x4*>(out + (row0 + rr) * (long)D + c0));
  }
}

extern "C" void kernel_launch(void* const* d_in, const int* in_sizes, int n_in,
                              void* d_out, int out_size, void* d_ws,
                              size_t ws_size, hipStream_t stream) {
  const float* h    = (const float*)d_in[0];
  const float* matA = (const float*)d_in[1];
  const float* matB = (const float*)d_in[2];
  float* out        = (float*)d_out;
  float* hr         = (float*)d_ws;   // M * RK * 4 = 1 MiB scratch

  hipLaunchKernelGGL(lora_k1, dim3((int)(M / 16)), dim3(256), 0, stream,
                     h, matB, hr);
  hipLaunchKernelGGL(lora_k2, dim3((int)(M / 64) * 4), dim3(256), 0, stream,
                     hr, matA, out);
}